// Round 2
// baseline (1277.574 us; speedup 1.0000x reference)
//
#include <hip/hip_runtime.h>
#include <math.h>

#define F_IN 256
#define HC   256   // H*C
#define H_   4
#define C_   64
#define KTOP 10
#define NEG_SLOPE 0.2f

// ================= GEMM: C[M,No] = A[M,K] @ B[No,K]^T (fp32) =================
// 128x128 tile, 8x8 per thread. Split column tile: Bs reads 2-way-aliased =
// free. Register diet keeps VGPR <=128 -> 4 blocks/CU.
#define BM 128
#define BN 128
#define BK 16
#define LDP (BM + 4)   // padded LDS leading dim (132%4==0 keeps float4 alignment)
__global__ __launch_bounds__(256) void gemm_nt(const float* __restrict__ A,
                                               const float* __restrict__ B,
                                               float* __restrict__ Cc,
                                               int M, int K, int No) {
  __shared__ float As[BK][LDP];
  __shared__ float Bs[BK][LDP];
  const int bm = blockIdx.x * BM;
  const int bn = blockIdx.y * BN;
  const int tid = threadIdx.x;
  const int tx = tid & 15, ty = tid >> 4;   // 16x16 compute grid
  const int lrow = tid >> 1;                // 0..127
  const int lk   = (tid & 1) << 3;          // 0 or 8
  const bool arow_ok = (bm + lrow < M);
  const float* aptr = A + (size_t)(bm + lrow) * K + lk;
  const float* bptr = B + (size_t)(bn + lrow) * K + lk;
  float acc[8][8] = {};
  for (int k0 = 0; k0 < K; k0 += BK) {
    float4 a0 = make_float4(0.f, 0.f, 0.f, 0.f), a1 = a0;
    if (arow_ok) {
      const float* ap = aptr + k0;
      a0 = *(const float4*)ap;
      a1 = *(const float4*)(ap + 4);
    }
    const float* bp = bptr + k0;
    float4 b0 = *(const float4*)bp;
    float4 b1 = *(const float4*)(bp + 4);
    __syncthreads();
    As[lk + 0][lrow] = a0.x; As[lk + 1][lrow] = a0.y; As[lk + 2][lrow] = a0.z; As[lk + 3][lrow] = a0.w;
    As[lk + 4][lrow] = a1.x; As[lk + 5][lrow] = a1.y; As[lk + 6][lrow] = a1.z; As[lk + 7][lrow] = a1.w;
    Bs[lk + 0][lrow] = b0.x; Bs[lk + 1][lrow] = b0.y; Bs[lk + 2][lrow] = b0.z; Bs[lk + 3][lrow] = b0.w;
    Bs[lk + 4][lrow] = b1.x; Bs[lk + 5][lrow] = b1.y; Bs[lk + 6][lrow] = b1.z; Bs[lk + 7][lrow] = b1.w;
    __syncthreads();
#pragma unroll
    for (int kk = 0; kk < BK; ++kk) {
      float a[8];
      *(float4*)&a[0] = *(const float4*)&As[kk][ty * 8];
      *(float4*)&a[4] = *(const float4*)&As[kk][ty * 8 + 4];
      {
        float4 bv = *(const float4*)&Bs[kk][tx * 4];
#pragma unroll
        for (int i = 0; i < 8; ++i) {
          acc[i][0] += a[i] * bv.x; acc[i][1] += a[i] * bv.y;
          acc[i][2] += a[i] * bv.z; acc[i][3] += a[i] * bv.w;
        }
      }
      {
        float4 bv = *(const float4*)&Bs[kk][64 + tx * 4];
#pragma unroll
        for (int i = 0; i < 8; ++i) {
          acc[i][4] += a[i] * bv.x; acc[i][5] += a[i] * bv.y;
          acc[i][6] += a[i] * bv.z; acc[i][7] += a[i] * bv.w;
        }
      }
    }
  }
#pragma unroll
  for (int i = 0; i < 8; ++i) {
    int r = bm + ty * 8 + i;
    if (r < M) {
      float* cp = Cc + (size_t)r * No + bn;
      *(float4*)(cp + tx * 4) = make_float4(acc[i][0], acc[i][1], acc[i][2], acc[i][3]);
      *(float4*)(cp + 64 + tx * 4) = make_float4(acc[i][4], acc[i][5], acc[i][6], acc[i][7]);
    }
  }
}

// ============ MLP layer 1: hid = relu(A @ B^T + bias), same tiling ============
__global__ __launch_bounds__(256) void gemm_bias_relu(const float* __restrict__ A,
                                                      const float* __restrict__ B,
                                                      const float* __restrict__ bias,
                                                      float* __restrict__ Cc,
                                                      int M, int K, int No) {
  __shared__ float As[BK][LDP];
  __shared__ float Bs[BK][LDP];
  const int bm = blockIdx.x * BM;
  const int bn = blockIdx.y * BN;
  const int tid = threadIdx.x;
  const int tx = tid & 15, ty = tid >> 4;
  const int lrow = tid >> 1;
  const int lk   = (tid & 1) << 3;
  const bool arow_ok = (bm + lrow < M);
  const bool brow_ok = (bn + lrow < No);
  const float* aptr = A + (size_t)(bm + lrow) * K + lk;
  const float* bptr = B + (size_t)(bn + lrow) * K + lk;
  float acc[8][8] = {};
  for (int k0 = 0; k0 < K; k0 += BK) {
    float4 a0 = make_float4(0.f, 0.f, 0.f, 0.f), a1 = a0, b0 = a0, b1 = a0;
    if (arow_ok) {
      const float* ap = aptr + k0;
      a0 = *(const float4*)ap;
      a1 = *(const float4*)(ap + 4);
    }
    if (brow_ok) {
      const float* bp = bptr + k0;
      b0 = *(const float4*)bp;
      b1 = *(const float4*)(bp + 4);
    }
    __syncthreads();
    As[lk + 0][lrow] = a0.x; As[lk + 1][lrow] = a0.y; As[lk + 2][lrow] = a0.z; As[lk + 3][lrow] = a0.w;
    As[lk + 4][lrow] = a1.x; As[lk + 5][lrow] = a1.y; As[lk + 6][lrow] = a1.z; As[lk + 7][lrow] = a1.w;
    Bs[lk + 0][lrow] = b0.x; Bs[lk + 1][lrow] = b0.y; Bs[lk + 2][lrow] = b0.z; Bs[lk + 3][lrow] = b0.w;
    Bs[lk + 4][lrow] = b1.x; Bs[lk + 5][lrow] = b1.y; Bs[lk + 6][lrow] = b1.z; Bs[lk + 7][lrow] = b1.w;
    __syncthreads();
#pragma unroll
    for (int kk = 0; kk < BK; ++kk) {
      float a[8];
      *(float4*)&a[0] = *(const float4*)&As[kk][ty * 8];
      *(float4*)&a[4] = *(const float4*)&As[kk][ty * 8 + 4];
      {
        float4 bv = *(const float4*)&Bs[kk][tx * 4];
#pragma unroll
        for (int i = 0; i < 8; ++i) {
          acc[i][0] += a[i] * bv.x; acc[i][1] += a[i] * bv.y;
          acc[i][2] += a[i] * bv.z; acc[i][3] += a[i] * bv.w;
        }
      }
      {
        float4 bv = *(const float4*)&Bs[kk][64 + tx * 4];
#pragma unroll
        for (int i = 0; i < 8; ++i) {
          acc[i][4] += a[i] * bv.x; acc[i][5] += a[i] * bv.y;
          acc[i][6] += a[i] * bv.z; acc[i][7] += a[i] * bv.w;
        }
      }
    }
  }
#pragma unroll
  for (int i = 0; i < 8; ++i) {
    int r = bm + ty * 8 + i;
    if (r < M) {
      float* cp = Cc + (size_t)r * No + bn;
#pragma unroll
      for (int j = 0; j < 4; ++j) {
        int col = tx * 4 + j;
        cp[col] = fmaxf(acc[i][j] + bias[bn + col], 0.f);
      }
#pragma unroll
      for (int j = 0; j < 4; ++j) {
        int col = 64 + tx * 4 + j;
        cp[col] = fmaxf(acc[i][4 + j] + bias[bn + col], 0.f);
      }
    }
  }
}

// ============ MLP layer 2: out[n,o] = <hid[n,:], Wl2[o,:]> + bl2[o] ============
__global__ __launch_bounds__(256) void head_out(const float* __restrict__ hid,
                                                const float* __restrict__ Wl2,
                                                const float* __restrict__ bl2,
                                                float* __restrict__ out, int n_nodes) {
  int t = blockIdx.x * 256 + threadIdx.x;
  int n = t >> 4, o = t & 15;
  if (n >= n_nodes) return;
  const float4* hp = (const float4*)(hid + (size_t)n * 128);
  const float4* wp = (const float4*)(Wl2 + (size_t)o * 128);
  float acc = bl2[o];
#pragma unroll
  for (int k = 0; k < 32; ++k) {
    float4 hv = hp[k], wv = wp[k];
    acc += hv.x * wv.x + hv.y * wv.y + hv.z * wv.z + hv.w * wv.w;
  }
  out[(size_t)n * 16 + o] = acc;
}

// =========== R14: exact (fp64) attention-score folds, both convs ===========
// conv1:  a1[n,h]   = sum_j x[n,j] * u1[h,j],     u1[h,j]   = sum_c W1[h*64+c,j]*att1[h,c]
// conv2:  a2[m,h']  = cst[h'] + sum_h sum_{i in keep(m,h)} w_i^h * zz[src_i,h,h']
//         zz[s,h,h']= sum_j x[s,j] * vv[h,h',j]
//         vv[h,h',j]= sum_c W1[h*64+c,j] * u2[h',h*64+c]
//         u2[h',k]  = sum_c W2[h'*64+c,k]*att2[h',c],   cst[h'] = sum_k b1[k]*u2[h',k]
// Everything fp64 => selection error ~1e-15, independent of our fp32 GEMM noise.

__global__ __launch_bounds__(256) void fold_att(const float* __restrict__ W,
                                                const float* __restrict__ att_s,
                                                const float* __restrict__ att_d,
                                                double* __restrict__ u_s,
                                                double* __restrict__ u_d) {
  int t = blockIdx.x * 256 + threadIdx.x;   // t = h*HC + k, total H_*HC = 1024
  if (t >= H_ * HC) return;
  int h = t >> 8;
  int k = t & (HC - 1);
  double s = 0.0, d = 0.0;
#pragma unroll 4
  for (int c = 0; c < C_; ++c) {
    double w = (double)W[(size_t)(h * C_ + c) * HC + k];
    s += w * (double)att_s[h * C_ + c];
    d += w * (double)att_d[h * C_ + c];
  }
  u_s[t] = s;
  u_d[t] = d;
}

// vv[type][h*4+h'][j] and cst[8] (cst[0..3]=s, cst[4..7]=d)
__global__ __launch_bounds__(256) void fold_vv(const float* __restrict__ W1,
                                               const double* __restrict__ u2s,
                                               const double* __restrict__ u2d,
                                               const float* __restrict__ b1,
                                               double* __restrict__ vvs,
                                               double* __restrict__ vvd,
                                               double* __restrict__ cst) {
  int t = blockIdx.x * 256 + threadIdx.x;
  if (t < 8192) {
    int type = t >> 12;          // 0=s, 1=d
    int rem = t & 4095;          // hh*256 + j
    int j = rem & 255;
    int hh = rem >> 8;           // h*4 + h'
    int h = hh >> 2, hp = hh & 3;
    const double* u2 = type ? u2d : u2s;
    double acc = 0.0;
#pragma unroll 4
    for (int c = 0; c < C_; ++c)
      acc += (double)W1[(size_t)(h * C_ + c) * HC + j] * u2[hp * HC + h * C_ + c];
    (type ? vvd : vvs)[(size_t)hh * HC + j] = acc;
  } else if (t < 8200) {
    int q = t - 8192;            // 0..7
    const double* u2 = (q >> 2) ? u2d : u2s;
    int hp = q & 3;
    double acc = 0.0;
    for (int k = 0; k < HC; ++k) acc += (double)b1[k] * u2[hp * HC + k];
    cst[q] = acc;
  }
}

// Fused per-node pass over x: conv1 scores (8 dots) + zz tensors (32 dots).
// One block per node, 4 waves x 10 combos; x row loaded once per lane.
__global__ __launch_bounds__(256) void scores1_zz(const float* __restrict__ x,
                                                  const double* __restrict__ u1s,
                                                  const double* __restrict__ u1d,
                                                  const double* __restrict__ vvs,
                                                  const double* __restrict__ vvd,
                                                  double* __restrict__ as1,
                                                  double* __restrict__ ad1,
                                                  double* __restrict__ zzs,
                                                  double* __restrict__ zzd, int n_nodes) {
  int n = blockIdx.x;
  if (n >= n_nodes) return;
  int w = threadIdx.x >> 6, lane = threadIdx.x & 63;
  const float* xp = x + (size_t)n * HC;
  double xv[4];
#pragma unroll
  for (int q = 0; q < 4; ++q) xv[q] = (double)xp[lane + 64 * q];
#pragma unroll
  for (int ci = 0; ci < 10; ++ci) {
    int c = w * 10 + ci;                      // 0..39, wave-uniform
    const double* wt;
    if (c < 8) {
      int type = c & 1, h = c >> 1;
      wt = (type ? u1d : u1s) + h * HC;
    } else {
      int cc = c - 8;
      int type = cc >> 4, hh = cc & 15;
      wt = (type ? vvd : vvs) + (size_t)hh * HC;
    }
    double acc = 0.0;
#pragma unroll
    for (int q = 0; q < 4; ++q) acc += xv[q] * wt[lane + 64 * q];
#pragma unroll
    for (int off = 32; off >= 1; off >>= 1) acc += __shfl_down(acc, off);
    if (lane == 0) {
      if (c < 8) {
        int type = c & 1, h = c >> 1;
        (type ? ad1 : as1)[n * H_ + h] = acc;
      } else {
        int cc = c - 8;
        int type = cc >> 4, hh = cc & 15;
        (type ? zzd : zzs)[(size_t)n * 16 + hh] = acc;
      }
    }
  }
}

// ====================== CSR build ======================
__global__ void count_edges(const int* __restrict__ dst, int E_, int* __restrict__ counts) {
  int e = blockIdx.x * blockDim.x + threadIdx.x;
  if (e < E_) atomicAdd(&counts[dst[e]], 1);
}

#define SCAN_T 1024
__global__ __launch_bounds__(SCAN_T) void scan_offsets(const int* __restrict__ counts,
                                                       int n_nodes, int* __restrict__ row_start,
                                                       int* __restrict__ wptr, int E_) {
  __shared__ int part[SCAN_T];
  int t = threadIdx.x;
  int chunk = (n_nodes + SCAN_T - 1) / SCAN_T;
  int lo = t * chunk;
  int hi = lo + chunk; if (hi > n_nodes) hi = n_nodes;
  int s = 0;
  for (int i = lo; i < hi; ++i) s += counts[i];
  part[t] = s;
  __syncthreads();
  for (int off = 1; off < SCAN_T; off <<= 1) {
    int v = (t >= off) ? part[t - off] : 0;
    __syncthreads();
    part[t] += v;
    __syncthreads();
  }
  int run = part[t] - s;   // exclusive prefix at chunk start
  for (int i = lo; i < hi; ++i) {
    int c = counts[i];
    row_start[i] = run;
    wptr[i] = run;
    run += c;
  }
  if (t == SCAN_T - 1) row_start[n_nodes] = E_;
}

__global__ void scatter_edges(const int* __restrict__ src, const int* __restrict__ dst, int E_,
                              int* __restrict__ wptr, int* __restrict__ csr_src) {
  int e = blockIdx.x * blockDim.x + threadIdx.x;
  if (e < E_) {
    int p = atomicAdd(&wptr[dst[e]], 1);
    csr_src[p] = src[e];
  }
}

// ====================== GAT aggregate (top-K softmax + gather) ======================
// fp64 scores -> exact top-K ordering (ties only between duplicate edges, whose
// contributions are identical). Softmax fp64; values aggregated fp32.
template <int W>
__device__ inline void bitonic_desc(double& v, int& l, int lane) {
#pragma unroll
  for (int k = 2; k <= W; k <<= 1) {
#pragma unroll
    for (int j = k >> 1; j > 0; j >>= 1) {
      double ov = __shfl_xor(v, j);
      int    ol = __shfl_xor(l, j);
      int partner = lane ^ j;
      bool dirDesc = ((lane & k) == 0);
      bool mineFirst = (v > ov) || (v == ov && l < ol);
      bool keepMine = (dirDesc == (lane < partner)) ? mineFirst : !mineFirst;
      if (!keepMine) { v = ov; l = ol; }
    }
  }
}

template <int CONCAT, int EMIT2>
__global__ __launch_bounds__(256) void gat_aggregate(const float* __restrict__ xl,
                                                     const double* __restrict__ as_,
                                                     const double* __restrict__ ad_,
                                                     const int* __restrict__ row_start,
                                                     const int* __restrict__ csr_src,
                                                     const float* __restrict__ bias,
                                                     float* __restrict__ out,
                                                     const double* __restrict__ zzs,
                                                     const double* __restrict__ zzd,
                                                     const double* __restrict__ cst,
                                                     double* __restrict__ as2,
                                                     double* __restrict__ ad2, int n_nodes) {
  __shared__ int    s_src[H_][16];
  __shared__ double s_w[H_][16];
  __shared__ float  s_out[H_][C_];
  __shared__ double s_p[H_][8];
  int n = blockIdx.x;
  int h = threadIdx.x >> 6;
  int lane = threadIdx.x & 63;
  int rs = row_start[n];
  int deg = row_start[n + 1] - rs;
  if (deg > 256) deg = 256;   // safety clamp; max expected deg ~50
  double adv = ad_[n * H_ + h];
  int kcount = deg < KTOP ? deg : KTOP;

  if (deg <= 64) {
    // ---- fast path: one candidate per lane, adaptive-width bitonic sort desc ----
    double v; int sv;
    if (lane < deg) {
      int s = csr_src[rs + lane];
      double a = as_[s * H_ + h] + adv;
      v = (a >= 0.0) ? a : (double)NEG_SLOPE * a;   // monotone: ordering exact
      sv = s;
    } else {
      v = -INFINITY; sv = -1;
    }
    int l = lane;
    if (deg <= 16)      bitonic_desc<16>(v, l, lane);
    else if (deg <= 32) bitonic_desc<32>(v, l, lane);
    else                bitonic_desc<64>(v, l, lane);
    int swin = __shfl(sv, l);   // winner's src id (pull from original lane)
    if (lane < kcount) {
      s_src[h][lane] = swin;
      s_w[h][lane] = v;
    }
  } else {
    // ---- fallback: iterative extraction (fp64) ----
    double av[4]; int svr[4];
#pragma unroll
    for (int q = 0; q < 4; ++q) {
      int idx = lane + (q << 6);
      if (idx < deg) {
        int s = csr_src[rs + idx];
        double a = as_[s * H_ + h] + adv;
        av[q] = (a >= 0.0) ? a : (double)NEG_SLOPE * a;
        svr[q] = s;
      } else {
        av[q] = -INFINITY; svr[q] = -1;
      }
    }
    for (int it = 0; it < kcount; ++it) {
      double best = av[0]; int bq = 0;
#pragma unroll
      for (int q = 1; q < 4; ++q)
        if (av[q] > best) { best = av[q]; bq = q; }
      double bv = best; int bl = lane;
#pragma unroll
      for (int off = 32; off >= 1; off >>= 1) {
        double ov = __shfl_down(bv, off);
        int    ol = __shfl_down(bl, off);
        if (ov > bv || (ov == bv && ol < bl)) { bv = ov; bl = ol; }
      }
      bl = __shfl(bl, 0);
      if (lane == bl) {
        s_src[h][it] = svr[bq];
        s_w[h][it] = best;
        av[bq] = -INFINITY;
      }
    }
  }
  __syncthreads();   // uniform: deg/kcount identical across the block's 4 waves

  // ---- softmax over kept edges (fp64) ----
  double m = (kcount > 0) ? s_w[h][0] : 0.0;   // first entry = max
  double ex = (lane < kcount) ? exp(s_w[h][lane] - m) : 0.0;
  double denom = ex;
#pragma unroll
  for (int off = 32; off >= 1; off >>= 1) denom += __shfl_down(denom, off);
  denom = __shfl(denom, 0);
  double inv = (kcount > 0) ? 1.0 / denom : 0.0;
  if (lane < kcount) s_w[h][lane] = ex * inv;
  __syncthreads();

  // ---- conv2 scores: a2[n,h'] = cst[h'] + sum_h sum_i w_i^h * zz[src_i,h,h'] ----
  if (EMIT2) {
    double ps[4] = {0.0, 0.0, 0.0, 0.0}, pd[4] = {0.0, 0.0, 0.0, 0.0};
    if (lane < kcount) {
      int s = s_src[h][lane];
      double wgt = s_w[h][lane];
      const double* zs = zzs + (size_t)s * 16 + h * 4;
      const double* zd = zzd + (size_t)s * 16 + h * 4;
#pragma unroll
      for (int p = 0; p < 4; ++p) { ps[p] = wgt * zs[p]; pd[p] = wgt * zd[p]; }
    }
#pragma unroll
    for (int off = 8; off >= 1; off >>= 1) {
#pragma unroll
      for (int p = 0; p < 4; ++p) {
        ps[p] += __shfl_down(ps[p], off);
        pd[p] += __shfl_down(pd[p], off);
      }
    }
    if (lane == 0) {
#pragma unroll
      for (int p = 0; p < 4; ++p) { s_p[h][p] = ps[p]; s_p[h][4 + p] = pd[p]; }
    }
    __syncthreads();
    if (h == 0 && lane < 8) {
      double v = s_p[0][lane] + s_p[1][lane] + s_p[2][lane] + s_p[3][lane] + cst[lane];
      if (lane < 4) as2[n * H_ + lane] = v;
      else          ad2[n * H_ + (lane - 4)] = v;
    }
  }

  // ---- aggregate: lane = channel ----
  float acc = 0.f;
  for (int i = 0; i < kcount; ++i) {
    int s = s_src[h][i];
    float w = (float)s_w[h][i];
    acc += w * xl[(size_t)s * HC + h * C_ + lane];
  }
  if (CONCAT) {
    out[(size_t)n * HC + h * C_ + lane] = acc + bias[h * C_ + lane];
  } else {
    s_out[h][lane] = acc;
    __syncthreads();
    if (h == 0) {
      float v2 = 0.25f * (s_out[0][lane] + s_out[1][lane] + s_out[2][lane] + s_out[3][lane]) +
                 bias[lane];
      out[(size_t)n * C_ + lane] = v2;
    }
  }
}

// ============================== launcher ==============================
extern "C" void kernel_launch(void* const* d_in, const int* in_sizes, int n_in,
                              void* d_out, int out_size, void* d_ws, size_t ws_size,
                              hipStream_t stream) {
  const float* x      = (const float*)d_in[0];
  const float* W1     = (const float*)d_in[1];
  const float* att_s1 = (const float*)d_in[2];
  const float* att_d1 = (const float*)d_in[3];
  const float* b1     = (const float*)d_in[4];
  const float* W2     = (const float*)d_in[5];
  const float* att_s2 = (const float*)d_in[6];
  const float* att_d2 = (const float*)d_in[7];
  const float* b2     = (const float*)d_in[8];
  const float* Wl1    = (const float*)d_in[9];
  const float* bl1    = (const float*)d_in[10];
  const float* Wl2    = (const float*)d_in[11];
  const float* bl2    = (const float*)d_in[12];
  const int*   eidx   = (const int*)d_in[13];

  const int N_ = in_sizes[0] / F_IN;     // 50000
  const int E_ = in_sizes[13] / 2;       // 800000
  const int* e_src = eidx;
  const int* e_dst = eidx + E_;

  // workspace layout
  char* base = (char*)d_ws;
  size_t off = 0;
  auto alloc = [&](size_t bytes) -> char* {
    char* p = base + off;
    off = (off + bytes + 255) & ~(size_t)255;
    return p;
  };
  float*  xl        = (float*)alloc((size_t)N_ * HC * 4);
  float*  hbuf      = (float*)alloc((size_t)N_ * HC * 4);   // h1; later h2 (N*64)
  double* as1       = (double*)alloc((size_t)N_ * H_ * 8);
  double* ad1       = (double*)alloc((size_t)N_ * H_ * 8);
  double* as2       = (double*)alloc((size_t)N_ * H_ * 8);
  double* ad2       = (double*)alloc((size_t)N_ * H_ * 8);
  double* zzs       = (double*)alloc((size_t)N_ * 16 * 8);
  double* zzd       = (double*)alloc((size_t)N_ * 16 * 8);
  double* u1s       = (double*)alloc((size_t)H_ * HC * 8);
  double* u1d       = (double*)alloc((size_t)H_ * HC * 8);
  double* u2s       = (double*)alloc((size_t)H_ * HC * 8);
  double* u2d       = (double*)alloc((size_t)H_ * HC * 8);
  double* vvs       = (double*)alloc((size_t)16 * HC * 8);
  double* vvd       = (double*)alloc((size_t)16 * HC * 8);
  double* cst       = (double*)alloc((size_t)8 * 8);
  int* counts       = (int*)alloc((size_t)N_ * 4);
  int* row_start    = (int*)alloc((size_t)(N_ + 1) * 4);
  int* wptr         = (int*)alloc((size_t)N_ * 4);
  int* csr_src      = (int*)alloc((size_t)E_ * 4);
  (void)ws_size;
  // hid buffer for MLP layer 1 reuses xl's space (xl is dead after gat_aggregate<0>)
  float* hidbuf  = xl;   // N*128 floats <= N*256 slot

  const int eb = (E_ + 255) / 256;

  // ---- CSR build (graph is shared by both conv layers) ----
  hipMemsetAsync(counts, 0, (size_t)N_ * 4, stream);
  count_edges<<<eb, 256, 0, stream>>>(e_dst, E_, counts);
  scan_offsets<<<1, SCAN_T, 0, stream>>>(counts, N_, row_start, wptr, E_);
  scatter_edges<<<eb, 256, 0, stream>>>(e_src, e_dst, E_, wptr, csr_src);

  // ---- fp64 score folds (tiny) ----
  fold_att<<<(H_ * HC + 255) / 256, 256, 0, stream>>>(W1, att_s1, att_d1, u1s, u1d);
  fold_att<<<(H_ * HC + 255) / 256, 256, 0, stream>>>(W2, att_s2, att_d2, u2s, u2d);
  fold_vv<<<(8200 + 255) / 256, 256, 0, stream>>>(W1, u2s, u2d, b1, vvs, vvd, cst);
  scores1_zz<<<N_, 256, 0, stream>>>(x, u1s, u1d, vvs, vvd, as1, ad1, zzs, zzd, N_);

  dim3 ggrid((N_ + BM - 1) / BM, HC / BN);

  // ---- conv1 (also emits exact conv2 scores) ----
  gemm_nt<<<ggrid, 256, 0, stream>>>(x, W1, xl, N_, F_IN, HC);
  gat_aggregate<1, 1><<<N_, 256, 0, stream>>>(xl, as1, ad1, row_start, csr_src, b1, hbuf,
                                              zzs, zzd, cst, as2, ad2, N_);

  // ---- conv2 ----
  gemm_nt<<<ggrid, 256, 0, stream>>>(hbuf, W2, xl, N_, HC, HC);
  gat_aggregate<0, 0><<<N_, 256, 0, stream>>>(xl, as2, ad2, row_start, csr_src, b2, hbuf,
                                              nullptr, nullptr, nullptr, nullptr, nullptr, N_);

  // ---- MLP head: hid = relu(h2 @ Wl1^T + bl1); out = hid @ Wl2^T + bl2 ----
  dim3 hgrid((N_ + BM - 1) / BM, 1);
  gemm_bias_relu<<<hgrid, 256, 0, stream>>>(hbuf, Wl1, bl1, hidbuf, N_, C_, 128);
  head_out<<<(N_ * 16 + 255) / 256, 256, 0, stream>>>(hidbuf, Wl2, bl2, (float*)d_out, N_);
}

// Round 3
// 1052.481 us; speedup vs baseline: 1.2139x; 1.2139x over previous
//
#include <hip/hip_runtime.h>
#include <math.h>

#define F_IN 256
#define HC   256   // H*C
#define H_   4
#define C_   64
#define KTOP 10
#define NEG_SLOPE 0.2f

// ================= GEMM: C[M,No] = A[M,K] @ B[No,K]^T (fp32) =================
// 128x128 tile, 8x8 per thread. Split column tile: Bs reads 2-way-aliased =
// free. Register diet keeps VGPR <=128 -> 4 blocks/CU.
#define BM 128
#define BN 128
#define BK 16
#define LDP (BM + 4)   // padded LDS leading dim (132%4==0 keeps float4 alignment)
__global__ __launch_bounds__(256) void gemm_nt(const float* __restrict__ A,
                                               const float* __restrict__ B,
                                               float* __restrict__ Cc,
                                               int M, int K, int No) {
  __shared__ float As[BK][LDP];
  __shared__ float Bs[BK][LDP];
  const int bm = blockIdx.x * BM;
  const int bn = blockIdx.y * BN;
  const int tid = threadIdx.x;
  const int tx = tid & 15, ty = tid >> 4;   // 16x16 compute grid
  const int lrow = tid >> 1;                // 0..127
  const int lk   = (tid & 1) << 3;          // 0 or 8
  const bool arow_ok = (bm + lrow < M);
  const float* aptr = A + (size_t)(bm + lrow) * K + lk;
  const float* bptr = B + (size_t)(bn + lrow) * K + lk;
  float acc[8][8] = {};
  for (int k0 = 0; k0 < K; k0 += BK) {
    float4 a0 = make_float4(0.f, 0.f, 0.f, 0.f), a1 = a0;
    if (arow_ok) {
      const float* ap = aptr + k0;
      a0 = *(const float4*)ap;
      a1 = *(const float4*)(ap + 4);
    }
    const float* bp = bptr + k0;
    float4 b0 = *(const float4*)bp;
    float4 b1 = *(const float4*)(bp + 4);
    __syncthreads();
    As[lk + 0][lrow] = a0.x; As[lk + 1][lrow] = a0.y; As[lk + 2][lrow] = a0.z; As[lk + 3][lrow] = a0.w;
    As[lk + 4][lrow] = a1.x; As[lk + 5][lrow] = a1.y; As[lk + 6][lrow] = a1.z; As[lk + 7][lrow] = a1.w;
    Bs[lk + 0][lrow] = b0.x; Bs[lk + 1][lrow] = b0.y; Bs[lk + 2][lrow] = b0.z; Bs[lk + 3][lrow] = b0.w;
    Bs[lk + 4][lrow] = b1.x; Bs[lk + 5][lrow] = b1.y; Bs[lk + 6][lrow] = b1.z; Bs[lk + 7][lrow] = b1.w;
    __syncthreads();
#pragma unroll
    for (int kk = 0; kk < BK; ++kk) {
      float a[8];
      *(float4*)&a[0] = *(const float4*)&As[kk][ty * 8];
      *(float4*)&a[4] = *(const float4*)&As[kk][ty * 8 + 4];
      {
        float4 bv = *(const float4*)&Bs[kk][tx * 4];
#pragma unroll
        for (int i = 0; i < 8; ++i) {
          acc[i][0] += a[i] * bv.x; acc[i][1] += a[i] * bv.y;
          acc[i][2] += a[i] * bv.z; acc[i][3] += a[i] * bv.w;
        }
      }
      {
        float4 bv = *(const float4*)&Bs[kk][64 + tx * 4];
#pragma unroll
        for (int i = 0; i < 8; ++i) {
          acc[i][4] += a[i] * bv.x; acc[i][5] += a[i] * bv.y;
          acc[i][6] += a[i] * bv.z; acc[i][7] += a[i] * bv.w;
        }
      }
    }
  }
#pragma unroll
  for (int i = 0; i < 8; ++i) {
    int r = bm + ty * 8 + i;
    if (r < M) {
      float* cp = Cc + (size_t)r * No + bn;
      *(float4*)(cp + tx * 4) = make_float4(acc[i][0], acc[i][1], acc[i][2], acc[i][3]);
      *(float4*)(cp + 64 + tx * 4) = make_float4(acc[i][4], acc[i][5], acc[i][6], acc[i][7]);
    }
  }
}

// ============ MLP layer 1: hid = relu(A @ B^T + bias), same tiling ============
__global__ __launch_bounds__(256) void gemm_bias_relu(const float* __restrict__ A,
                                                      const float* __restrict__ B,
                                                      const float* __restrict__ bias,
                                                      float* __restrict__ Cc,
                                                      int M, int K, int No) {
  __shared__ float As[BK][LDP];
  __shared__ float Bs[BK][LDP];
  const int bm = blockIdx.x * BM;
  const int bn = blockIdx.y * BN;
  const int tid = threadIdx.x;
  const int tx = tid & 15, ty = tid >> 4;
  const int lrow = tid >> 1;
  const int lk   = (tid & 1) << 3;
  const bool arow_ok = (bm + lrow < M);
  const bool brow_ok = (bn + lrow < No);
  const float* aptr = A + (size_t)(bm + lrow) * K + lk;
  const float* bptr = B + (size_t)(bn + lrow) * K + lk;
  float acc[8][8] = {};
  for (int k0 = 0; k0 < K; k0 += BK) {
    float4 a0 = make_float4(0.f, 0.f, 0.f, 0.f), a1 = a0, b0 = a0, b1 = a0;
    if (arow_ok) {
      const float* ap = aptr + k0;
      a0 = *(const float4*)ap;
      a1 = *(const float4*)(ap + 4);
    }
    if (brow_ok) {
      const float* bp = bptr + k0;
      b0 = *(const float4*)bp;
      b1 = *(const float4*)(bp + 4);
    }
    __syncthreads();
    As[lk + 0][lrow] = a0.x; As[lk + 1][lrow] = a0.y; As[lk + 2][lrow] = a0.z; As[lk + 3][lrow] = a0.w;
    As[lk + 4][lrow] = a1.x; As[lk + 5][lrow] = a1.y; As[lk + 6][lrow] = a1.z; As[lk + 7][lrow] = a1.w;
    Bs[lk + 0][lrow] = b0.x; Bs[lk + 1][lrow] = b0.y; Bs[lk + 2][lrow] = b0.z; Bs[lk + 3][lrow] = b0.w;
    Bs[lk + 4][lrow] = b1.x; Bs[lk + 5][lrow] = b1.y; Bs[lk + 6][lrow] = b1.z; Bs[lk + 7][lrow] = b1.w;
    __syncthreads();
#pragma unroll
    for (int kk = 0; kk < BK; ++kk) {
      float a[8];
      *(float4*)&a[0] = *(const float4*)&As[kk][ty * 8];
      *(float4*)&a[4] = *(const float4*)&As[kk][ty * 8 + 4];
      {
        float4 bv = *(const float4*)&Bs[kk][tx * 4];
#pragma unroll
        for (int i = 0; i < 8; ++i) {
          acc[i][0] += a[i] * bv.x; acc[i][1] += a[i] * bv.y;
          acc[i][2] += a[i] * bv.z; acc[i][3] += a[i] * bv.w;
        }
      }
      {
        float4 bv = *(const float4*)&Bs[kk][64 + tx * 4];
#pragma unroll
        for (int i = 0; i < 8; ++i) {
          acc[i][4] += a[i] * bv.x; acc[i][5] += a[i] * bv.y;
          acc[i][6] += a[i] * bv.z; acc[i][7] += a[i] * bv.w;
        }
      }
    }
  }
#pragma unroll
  for (int i = 0; i < 8; ++i) {
    int r = bm + ty * 8 + i;
    if (r < M) {
      float* cp = Cc + (size_t)r * No + bn;
#pragma unroll
      for (int j = 0; j < 4; ++j) {
        int col = tx * 4 + j;
        cp[col] = fmaxf(acc[i][j] + bias[bn + col], 0.f);
      }
#pragma unroll
      for (int j = 0; j < 4; ++j) {
        int col = 64 + tx * 4 + j;
        cp[col] = fmaxf(acc[i][4 + j] + bias[bn + col], 0.f);
      }
    }
  }
}

// ============ MLP layer 2: out[n,o] = <hid[n,:], Wl2[o,:]> + bl2[o] ============
__global__ __launch_bounds__(256) void head_out(const float* __restrict__ hid,
                                                const float* __restrict__ Wl2,
                                                const float* __restrict__ bl2,
                                                float* __restrict__ out, int n_nodes) {
  int t = blockIdx.x * 256 + threadIdx.x;
  int n = t >> 4, o = t & 15;
  if (n >= n_nodes) return;
  const float4* hp = (const float4*)(hid + (size_t)n * 128);
  const float4* wp = (const float4*)(Wl2 + (size_t)o * 128);
  float acc = bl2[o];
#pragma unroll
  for (int k = 0; k < 32; ++k) {
    float4 hv = hp[k], wv = wp[k];
    acc += hv.x * wv.x + hv.y * wv.y + hv.z * wv.z + hv.w * wv.w;
  }
  out[(size_t)n * 16 + o] = acc;
}

// =========== exact (fp64) attention-score folds, both convs ===========
// wt[40][256] packed fp64 weight matrix for the score GEMM:
//   rows 0..7  : c=2h+type -> u1 (type 0=s,1=d), u1[h,j]=sum_c W1[h*64+c,j]*att1[h,c]
//   rows 8..23 : vvs[hh], hh=h*4+h'
//   rows 24..39: vvd[hh]
// conv2: a2[m,h'] = cst[h'] + sum_h sum_{i in keep(m,h)} w_i^h * zz[src_i,h,h']
//        zz[s,hh] = sum_j x[s,j]*vv[hh,j];  vv[hh,j]=sum_c W1[h*64+c,j]*u2[h',h*64+c]
//        u2[h',k] = sum_c W2[h'*64+c,k]*att2[h',c];  cst[h'] = sum_k b1[k]*u2[h',k]
// All fp64 => selection error ~1e-15, independent of our fp32 GEMM noise.

// conv1 fold -> wt rows 0..7
__global__ __launch_bounds__(256) void fold_att1(const float* __restrict__ W1,
                                                 const float* __restrict__ att_s,
                                                 const float* __restrict__ att_d,
                                                 double* __restrict__ wt) {
  int t = blockIdx.x * 256 + threadIdx.x;   // t = h*HC + k, total 1024
  if (t >= H_ * HC) return;
  int h = t >> 8;
  int k = t & (HC - 1);
  double s = 0.0, d = 0.0;
#pragma unroll 4
  for (int c = 0; c < C_; ++c) {
    double w = (double)W1[(size_t)(h * C_ + c) * HC + k];
    s += w * (double)att_s[h * C_ + c];
    d += w * (double)att_d[h * C_ + c];
  }
  wt[(size_t)(2 * h + 0) * HC + k] = s;
  wt[(size_t)(2 * h + 1) * HC + k] = d;
}

// conv2 fold -> standalone u2 (consumed by fold_vv)
__global__ __launch_bounds__(256) void fold_att2(const float* __restrict__ W2,
                                                 const float* __restrict__ att_s,
                                                 const float* __restrict__ att_d,
                                                 double* __restrict__ u_s,
                                                 double* __restrict__ u_d) {
  int t = blockIdx.x * 256 + threadIdx.x;
  if (t >= H_ * HC) return;
  int h = t >> 8;
  int k = t & (HC - 1);
  double s = 0.0, d = 0.0;
#pragma unroll 4
  for (int c = 0; c < C_; ++c) {
    double w = (double)W2[(size_t)(h * C_ + c) * HC + k];
    s += w * (double)att_s[h * C_ + c];
    d += w * (double)att_d[h * C_ + c];
  }
  u_s[t] = s;
  u_d[t] = d;
}

// vv -> wt rows 8..39, plus cst[8] (cst[0..3]=s, cst[4..7]=d)
__global__ __launch_bounds__(256) void fold_vv(const float* __restrict__ W1,
                                               const double* __restrict__ u2s,
                                               const double* __restrict__ u2d,
                                               const float* __restrict__ b1,
                                               double* __restrict__ wt,
                                               double* __restrict__ cst) {
  int t = blockIdx.x * 256 + threadIdx.x;
  if (t < 8192) {
    int type = t >> 12;          // 0=s, 1=d
    int rem = t & 4095;          // hh*256 + j
    int j = rem & 255;
    int hh = rem >> 8;           // h*4 + h'
    int h = hh >> 2, hp = hh & 3;
    const double* u2 = type ? u2d : u2s;
    double acc = 0.0;
#pragma unroll 4
    for (int c = 0; c < C_; ++c)
      acc += (double)W1[(size_t)(h * C_ + c) * HC + j] * u2[hp * HC + h * C_ + c];
    wt[(size_t)(8 + type * 16 + hh) * HC + j] = acc;
  } else if (t < 8200) {
    int q = t - 8192;            // 0..7
    const double* u2 = (q >> 2) ? u2d : u2s;
    int hp = q & 3;
    double acc = 0.0;
    for (int k = 0; k < HC; ++k) acc += (double)b1[k] * u2[hp * HC + k];
    cst[q] = acc;
  }
}

// ====== R15: score GEMM — C[N,40] = x[N,256] . wt[40,256]^T, fp64 acc ======
// Replaces shuffle-bound scores1_zz (321us, 120 DS-pipe shuffles per 40 FMAs).
// Register-tiled: 256 threads cover 128 nodes x 40 combos; thread tile = 2x10
// (12 LDS reads per 20 fp64 FMAs, all reads broadcast or conflict-free via +1
// pad). Accumulation per (n,c) is strictly k-ascending fp64 -> same ~1e-15
// exactness as before.
#define SNB 128
#define SKB 32
__global__ __launch_bounds__(256) void scores_gemm(const float* __restrict__ x,
                                                   const double* __restrict__ wt,
                                                   double* __restrict__ as1,
                                                   double* __restrict__ ad1,
                                                   double* __restrict__ zzs,
                                                   double* __restrict__ zzd, int n_nodes) {
  __shared__ float  Xs[SNB][SKB + 1];
  __shared__ double Ws[40][SKB + 1];
  const int tid = threadIdx.x;
  const int n0 = blockIdx.x * SNB;
  const int g = tid & 3;          // combo group: combos g*10 .. g*10+9
  const int p = tid >> 2;         // node pair 0..63 -> rows 2p, 2p+1
  double acc0[10] = {}, acc1[10] = {};
  for (int k0 = 0; k0 < HC; k0 += SKB) {
    __syncthreads();   // previous tile's reads done before overwrite
    {
      // stage x tile: thread loads 16 consecutive floats of row (tid>>1)
      int row = tid >> 1;
      int colb = (tid & 1) * 16;
      float* d = &Xs[row][colb];
      int n = n0 + row;
      if (n < n_nodes) {
        const float* xp = x + (size_t)n * HC + k0 + colb;
        float4 v0 = *(const float4*)(xp);
        float4 v1 = *(const float4*)(xp + 4);
        float4 v2 = *(const float4*)(xp + 8);
        float4 v3 = *(const float4*)(xp + 12);
        d[0] = v0.x;  d[1] = v0.y;  d[2] = v0.z;  d[3] = v0.w;
        d[4] = v1.x;  d[5] = v1.y;  d[6] = v1.z;  d[7] = v1.w;
        d[8] = v2.x;  d[9] = v2.y;  d[10] = v2.z; d[11] = v2.w;
        d[12] = v3.x; d[13] = v3.y; d[14] = v3.z; d[15] = v3.w;
      } else {
#pragma unroll
        for (int j = 0; j < 16; ++j) d[j] = 0.f;
      }
    }
#pragma unroll
    for (int q = 0; q < 5; ++q) {   // stage wt tile: 40x32 doubles
      int idx = tid + q * 256;      // 0..1279
      int row = idx >> 5, col = idx & 31;
      Ws[row][col] = wt[(size_t)row * HC + k0 + col];
    }
    __syncthreads();
#pragma unroll
    for (int kk = 0; kk < SKB; ++kk) {
      double xv0 = (double)Xs[2 * p][kk];
      double xv1 = (double)Xs[2 * p + 1][kk];
#pragma unroll
      for (int ci = 0; ci < 10; ++ci) {
        double w = Ws[g * 10 + ci][kk];
        acc0[ci] += xv0 * w;
        acc1[ci] += xv1 * w;
      }
    }
  }
  const int na = n0 + 2 * p;
  const int nb = na + 1;
  if (na < n_nodes) {
#pragma unroll
    for (int ci = 0; ci < 10; ++ci) {
      int c = g * 10 + ci;
      double v = acc0[ci];
      if (c < 8)        ((c & 1) ? ad1 : as1)[na * H_ + (c >> 1)] = v;
      else if (c < 24)  zzs[(size_t)na * 16 + (c - 8)] = v;
      else              zzd[(size_t)na * 16 + (c - 24)] = v;
    }
  }
  if (nb < n_nodes) {
#pragma unroll
    for (int ci = 0; ci < 10; ++ci) {
      int c = g * 10 + ci;
      double v = acc1[ci];
      if (c < 8)        ((c & 1) ? ad1 : as1)[nb * H_ + (c >> 1)] = v;
      else if (c < 24)  zzs[(size_t)nb * 16 + (c - 8)] = v;
      else              zzd[(size_t)nb * 16 + (c - 24)] = v;
    }
  }
}

// ====================== CSR build ======================
__global__ void count_edges(const int* __restrict__ dst, int E_, int* __restrict__ counts) {
  int e = blockIdx.x * blockDim.x + threadIdx.x;
  if (e < E_) atomicAdd(&counts[dst[e]], 1);
}

#define SCAN_T 1024
__global__ __launch_bounds__(SCAN_T) void scan_offsets(const int* __restrict__ counts,
                                                       int n_nodes, int* __restrict__ row_start,
                                                       int* __restrict__ wptr, int E_) {
  __shared__ int part[SCAN_T];
  int t = threadIdx.x;
  int chunk = (n_nodes + SCAN_T - 1) / SCAN_T;
  int lo = t * chunk;
  int hi = lo + chunk; if (hi > n_nodes) hi = n_nodes;
  int s = 0;
  for (int i = lo; i < hi; ++i) s += counts[i];
  part[t] = s;
  __syncthreads();
  for (int off = 1; off < SCAN_T; off <<= 1) {
    int v = (t >= off) ? part[t - off] : 0;
    __syncthreads();
    part[t] += v;
    __syncthreads();
  }
  int run = part[t] - s;   // exclusive prefix at chunk start
  for (int i = lo; i < hi; ++i) {
    int c = counts[i];
    row_start[i] = run;
    wptr[i] = run;
    run += c;
  }
  if (t == SCAN_T - 1) row_start[n_nodes] = E_;
}

__global__ void scatter_edges(const int* __restrict__ src, const int* __restrict__ dst, int E_,
                              int* __restrict__ wptr, int* __restrict__ csr_src) {
  int e = blockIdx.x * blockDim.x + threadIdx.x;
  if (e < E_) {
    int p = atomicAdd(&wptr[dst[e]], 1);
    csr_src[p] = src[e];
  }
}

// ====================== GAT aggregate (top-K softmax + gather) ======================
// fp64 scores -> exact top-K ordering (ties only between duplicate edges, whose
// contributions are identical). Softmax fp64; values aggregated fp32.
template <int W>
__device__ inline void bitonic_desc(double& v, int& l, int lane) {
#pragma unroll
  for (int k = 2; k <= W; k <<= 1) {
#pragma unroll
    for (int j = k >> 1; j > 0; j >>= 1) {
      double ov = __shfl_xor(v, j);
      int    ol = __shfl_xor(l, j);
      int partner = lane ^ j;
      bool dirDesc = ((lane & k) == 0);
      bool mineFirst = (v > ov) || (v == ov && l < ol);
      bool keepMine = (dirDesc == (lane < partner)) ? mineFirst : !mineFirst;
      if (!keepMine) { v = ov; l = ol; }
    }
  }
}

template <int CONCAT, int EMIT2>
__global__ __launch_bounds__(256) void gat_aggregate(const float* __restrict__ xl,
                                                     const double* __restrict__ as_,
                                                     const double* __restrict__ ad_,
                                                     const int* __restrict__ row_start,
                                                     const int* __restrict__ csr_src,
                                                     const float* __restrict__ bias,
                                                     float* __restrict__ out,
                                                     const double* __restrict__ zzs,
                                                     const double* __restrict__ zzd,
                                                     const double* __restrict__ cst,
                                                     double* __restrict__ as2,
                                                     double* __restrict__ ad2, int n_nodes) {
  __shared__ int    s_src[H_][16];
  __shared__ double s_w[H_][16];
  __shared__ float  s_out[H_][C_];
  __shared__ double s_p[H_][8];
  int n = blockIdx.x;
  int h = threadIdx.x >> 6;
  int lane = threadIdx.x & 63;
  int rs = row_start[n];
  int deg = row_start[n + 1] - rs;
  if (deg > 256) deg = 256;   // safety clamp; max expected deg ~50
  double adv = ad_[n * H_ + h];
  int kcount = deg < KTOP ? deg : KTOP;

  if (deg <= 64) {
    // ---- fast path: one candidate per lane, adaptive-width bitonic sort desc ----
    double v; int sv;
    if (lane < deg) {
      int s = csr_src[rs + lane];
      double a = as_[s * H_ + h] + adv;
      v = (a >= 0.0) ? a : (double)NEG_SLOPE * a;   // monotone: ordering exact
      sv = s;
    } else {
      v = -INFINITY; sv = -1;
    }
    int l = lane;
    if (deg <= 16)      bitonic_desc<16>(v, l, lane);
    else if (deg <= 32) bitonic_desc<32>(v, l, lane);
    else                bitonic_desc<64>(v, l, lane);
    int swin = __shfl(sv, l);   // winner's src id (pull from original lane)
    if (lane < kcount) {
      s_src[h][lane] = swin;
      s_w[h][lane] = v;
    }
  } else {
    // ---- fallback: iterative extraction (fp64) ----
    double av[4]; int svr[4];
#pragma unroll
    for (int q = 0; q < 4; ++q) {
      int idx = lane + (q << 6);
      if (idx < deg) {
        int s = csr_src[rs + idx];
        double a = as_[s * H_ + h] + adv;
        av[q] = (a >= 0.0) ? a : (double)NEG_SLOPE * a;
        svr[q] = s;
      } else {
        av[q] = -INFINITY; svr[q] = -1;
      }
    }
    for (int it = 0; it < kcount; ++it) {
      double best = av[0]; int bq = 0;
#pragma unroll
      for (int q = 1; q < 4; ++q)
        if (av[q] > best) { best = av[q]; bq = q; }
      double bv = best; int bl = lane;
#pragma unroll
      for (int off = 32; off >= 1; off >>= 1) {
        double ov = __shfl_down(bv, off);
        int    ol = __shfl_down(bl, off);
        if (ov > bv || (ov == bv && ol < bl)) { bv = ov; bl = ol; }
      }
      bl = __shfl(bl, 0);
      if (lane == bl) {
        s_src[h][it] = svr[bq];
        s_w[h][it] = best;
        av[bq] = -INFINITY;
      }
    }
  }
  __syncthreads();   // uniform: deg/kcount identical across the block's 4 waves

  // ---- softmax over kept edges (fp64) ----
  double m = (kcount > 0) ? s_w[h][0] : 0.0;   // first entry = max
  double ex = (lane < kcount) ? exp(s_w[h][lane] - m) : 0.0;
  double denom = ex;
#pragma unroll
  for (int off = 32; off >= 1; off >>= 1) denom += __shfl_down(denom, off);
  denom = __shfl(denom, 0);
  double inv = (kcount > 0) ? 1.0 / denom : 0.0;
  if (lane < kcount) s_w[h][lane] = ex * inv;
  __syncthreads();

  // ---- conv2 scores: a2[n,h'] = cst[h'] + sum_h sum_i w_i^h * zz[src_i,h,h'] ----
  if (EMIT2) {
    double ps[4] = {0.0, 0.0, 0.0, 0.0}, pd[4] = {0.0, 0.0, 0.0, 0.0};
    if (lane < kcount) {
      int s = s_src[h][lane];
      double wgt = s_w[h][lane];
      const double* zs = zzs + (size_t)s * 16 + h * 4;
      const double* zd = zzd + (size_t)s * 16 + h * 4;
#pragma unroll
      for (int p = 0; p < 4; ++p) { ps[p] = wgt * zs[p]; pd[p] = wgt * zd[p]; }
    }
#pragma unroll
    for (int off = 8; off >= 1; off >>= 1) {
#pragma unroll
      for (int p = 0; p < 4; ++p) {
        ps[p] += __shfl_down(ps[p], off);
        pd[p] += __shfl_down(pd[p], off);
      }
    }
    if (lane == 0) {
#pragma unroll
      for (int p = 0; p < 4; ++p) { s_p[h][p] = ps[p]; s_p[h][4 + p] = pd[p]; }
    }
    __syncthreads();
    if (h == 0 && lane < 8) {
      double v = s_p[0][lane] + s_p[1][lane] + s_p[2][lane] + s_p[3][lane] + cst[lane];
      if (lane < 4) as2[n * H_ + lane] = v;
      else          ad2[n * H_ + (lane - 4)] = v;
    }
  }

  // ---- aggregate: lane = channel ----
  float acc = 0.f;
  for (int i = 0; i < kcount; ++i) {
    int s = s_src[h][i];
    float w = (float)s_w[h][i];
    acc += w * xl[(size_t)s * HC + h * C_ + lane];
  }
  if (CONCAT) {
    out[(size_t)n * HC + h * C_ + lane] = acc + bias[h * C_ + lane];
  } else {
    s_out[h][lane] = acc;
    __syncthreads();
    if (h == 0) {
      float v2 = 0.25f * (s_out[0][lane] + s_out[1][lane] + s_out[2][lane] + s_out[3][lane]) +
                 bias[lane];
      out[(size_t)n * C_ + lane] = v2;
    }
  }
}

// ============================== launcher ==============================
extern "C" void kernel_launch(void* const* d_in, const int* in_sizes, int n_in,
                              void* d_out, int out_size, void* d_ws, size_t ws_size,
                              hipStream_t stream) {
  const float* x      = (const float*)d_in[0];
  const float* W1     = (const float*)d_in[1];
  const float* att_s1 = (const float*)d_in[2];
  const float* att_d1 = (const float*)d_in[3];
  const float* b1     = (const float*)d_in[4];
  const float* W2     = (const float*)d_in[5];
  const float* att_s2 = (const float*)d_in[6];
  const float* att_d2 = (const float*)d_in[7];
  const float* b2     = (const float*)d_in[8];
  const float* Wl1    = (const float*)d_in[9];
  const float* bl1    = (const float*)d_in[10];
  const float* Wl2    = (const float*)d_in[11];
  const float* bl2    = (const float*)d_in[12];
  const int*   eidx   = (const int*)d_in[13];

  const int N_ = in_sizes[0] / F_IN;     // 50000
  const int E_ = in_sizes[13] / 2;       // 800000
  const int* e_src = eidx;
  const int* e_dst = eidx + E_;

  // workspace layout
  char* base = (char*)d_ws;
  size_t off = 0;
  auto alloc = [&](size_t bytes) -> char* {
    char* p = base + off;
    off = (off + bytes + 255) & ~(size_t)255;
    return p;
  };
  float*  xl        = (float*)alloc((size_t)N_ * HC * 4);
  float*  hbuf      = (float*)alloc((size_t)N_ * HC * 4);   // h1; later h2 (N*64)
  double* as1       = (double*)alloc((size_t)N_ * H_ * 8);
  double* ad1       = (double*)alloc((size_t)N_ * H_ * 8);
  double* as2       = (double*)alloc((size_t)N_ * H_ * 8);
  double* ad2       = (double*)alloc((size_t)N_ * H_ * 8);
  double* zzs       = (double*)alloc((size_t)N_ * 16 * 8);
  double* zzd       = (double*)alloc((size_t)N_ * 16 * 8);
  double* wt        = (double*)alloc((size_t)40 * HC * 8);
  double* u2s       = (double*)alloc((size_t)H_ * HC * 8);
  double* u2d       = (double*)alloc((size_t)H_ * HC * 8);
  double* cst       = (double*)alloc((size_t)8 * 8);
  int* counts       = (int*)alloc((size_t)N_ * 4);
  int* row_start    = (int*)alloc((size_t)(N_ + 1) * 4);
  int* wptr         = (int*)alloc((size_t)N_ * 4);
  int* csr_src      = (int*)alloc((size_t)E_ * 4);
  (void)ws_size;
  // hid buffer for MLP layer 1 reuses xl's space (xl is dead after gat_aggregate<0>)
  float* hidbuf  = xl;   // N*128 floats <= N*256 slot

  const int eb = (E_ + 255) / 256;

  // ---- CSR build (graph is shared by both conv layers) ----
  hipMemsetAsync(counts, 0, (size_t)N_ * 4, stream);
  count_edges<<<eb, 256, 0, stream>>>(e_dst, E_, counts);
  scan_offsets<<<1, SCAN_T, 0, stream>>>(counts, N_, row_start, wptr, E_);
  scatter_edges<<<eb, 256, 0, stream>>>(e_src, e_dst, E_, wptr, csr_src);

  // ---- fp64 score folds (tiny) ----
  fold_att1<<<(H_ * HC + 255) / 256, 256, 0, stream>>>(W1, att_s1, att_d1, wt);
  fold_att2<<<(H_ * HC + 255) / 256, 256, 0, stream>>>(W2, att_s2, att_d2, u2s, u2d);
  fold_vv<<<(8200 + 255) / 256, 256, 0, stream>>>(W1, u2s, u2d, b1, wt, cst);
  scores_gemm<<<(N_ + SNB - 1) / SNB, 256, 0, stream>>>(x, wt, as1, ad1, zzs, zzd, N_);

  dim3 ggrid((N_ + BM - 1) / BM, HC / BN);

  // ---- conv1 (also emits exact conv2 scores) ----
  gemm_nt<<<ggrid, 256, 0, stream>>>(x, W1, xl, N_, F_IN, HC);
  gat_aggregate<1, 1><<<N_, 256, 0, stream>>>(xl, as1, ad1, row_start, csr_src, b1, hbuf,
                                              zzs, zzd, cst, as2, ad2, N_);

  // ---- conv2 ----
  gemm_nt<<<ggrid, 256, 0, stream>>>(hbuf, W2, xl, N_, HC, HC);
  gat_aggregate<0, 0><<<N_, 256, 0, stream>>>(xl, as2, ad2, row_start, csr_src, b2, hbuf,
                                              nullptr, nullptr, nullptr, nullptr, nullptr, N_);

  // ---- MLP head: hid = relu(h2 @ Wl1^T + bl1); out = hid @ Wl2^T + bl2 ----
  dim3 hgrid((N_ + BM - 1) / BM, 1);
  gemm_bias_relu<<<hgrid, 256, 0, stream>>>(hbuf, Wl1, bl1, hidbuf, N_, C_, 128);
  head_out<<<(N_ * 16 + 255) / 256, 256, 0, stream>>>(hidbuf, Wl2, bl2, (float*)d_out, N_);
}